// Round 4
// baseline (1040.339 us; speedup 1.0000x reference)
//
#include <hip/hip_runtime.h>
#include <math.h>

// DeepseekV2 MoE gate, MI355X.
// Stage 1: exact fp64-accumulated router GEMM  logits = X[16384,5120] @ W[160,5120]^T.
// Stage 2: cast logits to fp32 and EMULATE the reference's fp32 pipeline
//   (softmax in fp32, group-max / top-3 groups / top-6 experts ranked on fp32
//   scores with stable tie -> lower index). Rationale: the harness ref computes
//   logits at high precision but softmax/top_k in fp32; at ~1 token the rank
//   boundary is an exact fp32 TIE that stable top_k breaks by index. Ranking by
//   exact value missed it twice (absmax=32 in both fp32 and fp64 runs).

#define TT    16384
#define HH    5120
#define EE    160
#define BT    32         // tokens per block
#define BK    32         // K tile
#define NT    (HH / BK)  // 160
#define SXLD  36         // x LDS stride (floats): keeps 16B-aligned b128 reads
#define SWLD  161        // w LDS stride (floats): (k+e)%32 -> conflict-free
#define SLF   161        // fp32 logit LDS stride (floats)
#define TOPK  6

__device__ __forceinline__ bool betterf(float va, int ia, float vb, int ib) {
    return (va > vb) || ((va == vb) && (ia < ib));
}

__global__ __launch_bounds__(256)
void gate_kernel(const float* __restrict__ X, const float* __restrict__ W,
                 float* __restrict__ out) {
    // GEMM staging: 2*32*36*4 + 2*32*161*4 = 50432 B.
    // Epilogue reuses the same bytes as [32][161] floats (20608 B).
    __shared__ __align__(16) unsigned char smem_raw[2*BK*SXLD*4 + 2*BK*SWLD*4];
    float* sx    = (float*)smem_raw;            // [2][BK][SXLD]  x^T: [k][tok]
    float* sw    = sx + 2 * BK * SXLD;          // [2][BK][SWLD]  w^T: [k][e]
    float* slogf = (float*)smem_raw;            // [BT][SLF]      fp32 logits

    const int tid = threadIdx.x;
    const int tx  = tid & 31;                   // experts {tx+32m}
    const int ty  = tid >> 5;                   // tokens  {4ty..4ty+3}
    const long tok0 = (long)blockIdx.x * BT;

    double acc[4][5];
    #pragma unroll
    for (int j = 0; j < 4; ++j)
        #pragma unroll
        for (int m = 0; m < 5; ++m) acc[j][m] = 0.0;

    float4 px, pw[5];

    // ---- prologue: tile 0 -> regs -> LDS buf0
    {
        int i = tid, tl = i >> 3, k4 = (i & 7) << 2;
        px = *(const float4*)(X + (tok0 + tl) * HH + k4);
        #pragma unroll
        for (int r = 0; r < 5; ++r) {
            int q = tid + 256 * r, e = q >> 3, kk = (q & 7) << 2;
            pw[r] = *(const float4*)(W + (long)e * HH + kk);
        }
        sx[(k4 + 0) * SXLD + tl] = px.x;
        sx[(k4 + 1) * SXLD + tl] = px.y;
        sx[(k4 + 2) * SXLD + tl] = px.z;
        sx[(k4 + 3) * SXLD + tl] = px.w;
        #pragma unroll
        for (int r = 0; r < 5; ++r) {
            int q = tid + 256 * r, e = q >> 3, kk = (q & 7) << 2;
            sw[(kk + 0) * SWLD + e] = pw[r].x;
            sw[(kk + 1) * SWLD + e] = pw[r].y;
            sw[(kk + 2) * SWLD + e] = pw[r].z;
            sw[(kk + 3) * SWLD + e] = pw[r].w;
        }
    }
    __syncthreads();

    // ---- main K loop: prefetch(t+1)->regs, compute(t) in fp64, regs->LDS
    for (int t = 0; t < NT; ++t) {
        const int cur = t & 1;
        if (t + 1 < NT) {
            const int k0 = (t + 1) * BK;
            int i = tid, tl = i >> 3, k4 = (i & 7) << 2;
            px = *(const float4*)(X + (tok0 + tl) * HH + k0 + k4);
            #pragma unroll
            for (int r = 0; r < 5; ++r) {
                int q = tid + 256 * r, e = q >> 3, kk = (q & 7) << 2;
                pw[r] = *(const float4*)(W + (long)e * HH + k0 + kk);
            }
        }
        const float* bx = sx + cur * (BK * SXLD);
        const float* bw = sw + cur * (BK * SWLD);
        #pragma unroll 4
        for (int k = 0; k < BK; ++k) {
            float4 xa = *(const float4*)(bx + k * SXLD + 4 * ty);
            double xd[4] = {(double)xa.x, (double)xa.y, (double)xa.z, (double)xa.w};
            double wd[5];
            #pragma unroll
            for (int m = 0; m < 5; ++m) wd[m] = (double)bw[k * SWLD + tx + 32 * m];
            #pragma unroll
            for (int j = 0; j < 4; ++j)
                #pragma unroll
                for (int m = 0; m < 5; ++m)
                    acc[j][m] = fma(xd[j], wd[m], acc[j][m]);
        }
        if (t + 1 < NT) {
            const int nb = (t + 1) & 1;
            float* wxp = sx + nb * (BK * SXLD);
            float* wwp = sw + nb * (BK * SWLD);
            int i = tid, tl = i >> 3, k4 = (i & 7) << 2;
            wxp[(k4 + 0) * SXLD + tl] = px.x;
            wxp[(k4 + 1) * SXLD + tl] = px.y;
            wxp[(k4 + 2) * SXLD + tl] = px.z;
            wxp[(k4 + 3) * SXLD + tl] = px.w;
            #pragma unroll
            for (int r = 0; r < 5; ++r) {
                int q = tid + 256 * r, e = q >> 3, kk = (q & 7) << 2;
                wwp[(kk + 0) * SWLD + e] = pw[r].x;
                wwp[(kk + 1) * SWLD + e] = pw[r].y;
                wwp[(kk + 2) * SWLD + e] = pw[r].z;
                wwp[(kk + 3) * SWLD + e] = pw[r].w;
            }
        }
        __syncthreads();
    }

    // ---- epilogue: exact logits, correctly rounded to fp32, -> LDS
    #pragma unroll
    for (int j = 0; j < 4; ++j)
        #pragma unroll
        for (int m = 0; m < 5; ++m)
            slogf[(4 * ty + j) * SLF + tx + 32 * m] = (float)acc[j][m];
    __syncthreads();

    // ---- fp32 reference-pipeline emulation. 8 lanes/token; lane `sub` owns
    //      group `sub` = experts [20*sub, 20*sub+20).
    const int token = tid >> 3;
    const int sub   = tid & 7;
    const float* rowp = slogf + token * SLF + sub * 20;
    float l[20];
    #pragma unroll
    for (int i = 0; i < 20; ++i) l[i] = rowp[i];

    // row max over 160 in fp32 (max is exact & order-free)
    float gm = l[0];
    #pragma unroll
    for (int i = 1; i < 20; ++i) gm = fmaxf(gm, l[i]);
    float mxf = gm;
    mxf = fmaxf(mxf, __shfl_xor(mxf, 1));
    mxf = fmaxf(mxf, __shfl_xor(mxf, 2));
    mxf = fmaxf(mxf, __shfl_xor(mxf, 4));

    // fp32 softmax: e = expf(l - mx); s = e / sum(e)
    #pragma unroll
    for (int i = 0; i < 20; ++i) l[i] = expf(l[i] - mxf);
    float sef = 0.f;
    #pragma unroll
    for (int i = 0; i < 20; ++i) sef += l[i];
    sef += __shfl_xor(sef, 1);
    sef += __shfl_xor(sef, 2);
    sef += __shfl_xor(sef, 4);
    #pragma unroll
    for (int i = 0; i < 20; ++i) l[i] = l[i] / sef;   // l[] now = fp32 scores

    // group score = fp32 max of this lane's 20 scores
    float gs = l[0];
    #pragma unroll
    for (int i = 1; i < 20; ++i) gs = fmaxf(gs, l[i]);

    // gather all 8 group scores (static 3-stage butterfly)
    float a0 = gs;
    float a1 = __shfl_xor(a0, 1);
    float a2 = __shfl_xor(a0, 2), a3 = __shfl_xor(a1, 2);
    float a4 = __shfl_xor(a0, 4), a5 = __shfl_xor(a1, 4);
    float a6 = __shfl_xor(a2, 4), a7 = __shfl_xor(a3, 4);
    float gv[8] = {a0, a1, a2, a3, a4, a5, a6, a7};
    int   gi[8] = {sub, sub^1, sub^2, sub^3, sub^4, sub^5, sub^6, sub^7};

    // top-3 groups on fp32 scores, tie -> lower group id
    int tg0, tg1, tg2;
    {
        float bv; int bi;
        bv = gv[0]; bi = gi[0];
        #pragma unroll
        for (int q = 1; q < 8; ++q) if (betterf(gv[q], gi[q], bv, bi)) { bv = gv[q]; bi = gi[q]; }
        tg0 = bi;
        #pragma unroll
        for (int q = 0; q < 8; ++q) if (gi[q] == tg0) gv[q] = -INFINITY;
        bv = gv[0]; bi = gi[0];
        #pragma unroll
        for (int q = 1; q < 8; ++q) if (betterf(gv[q], gi[q], bv, bi)) { bv = gv[q]; bi = gi[q]; }
        tg1 = bi;
        #pragma unroll
        for (int q = 0; q < 8; ++q) if (gi[q] == tg1) gv[q] = -INFINITY;
        bv = gv[0]; bi = gi[0];
        #pragma unroll
        for (int q = 1; q < 8; ++q) if (betterf(gv[q], gi[q], bv, bi)) { bv = gv[q]; bi = gi[q]; }
        tg2 = bi;
    }
    const bool allowed = (sub == tg0) || (sub == tg1) || (sub == tg2);

    // lane-local top-6 of this lane's 20 fp32 scores (masked lanes -> -inf)
    float v[6]; int ix[6];
    #pragma unroll
    for (int j = 0; j < 6; ++j) { v[j] = -INFINITY; ix[j] = 1 << 30; }
    #pragma unroll
    for (int i = 0; i < 20; ++i) {
        const float val = allowed ? l[i] : -INFINITY;
        const int   idx = sub * 20 + i;
        if (betterf(val, idx, v[5], ix[5])) {
            v[5] = val; ix[5] = idx;
            #pragma unroll
            for (int j = 5; j >= 1; --j)
                if (betterf(v[j], ix[j], v[j-1], ix[j-1])) {
                    float tv = v[j]; v[j] = v[j-1]; v[j-1] = tv;
                    int   ti = ix[j]; ix[j] = ix[j-1]; ix[j-1] = ti;
                }
        }
    }

    // butterfly merge across the 8 lanes (disjoint expert ranges)
    #pragma unroll
    for (int st = 1; st <= 4; st <<= 1) {
        float pv[6]; int pix[6];
        #pragma unroll
        for (int j = 0; j < 6; ++j) {
            pv[j]  = __shfl_xor(v[j], st);
            pix[j] = __shfl_xor(ix[j], st);
        }
        #pragma unroll
        for (int j = 0; j < 6; ++j) {
            const float val = pv[j]; const int idx = pix[j];
            if (betterf(val, idx, v[5], ix[5])) {
                v[5] = val; ix[5] = idx;
                #pragma unroll
                for (int q = 5; q >= 1; --q)
                    if (betterf(v[q], ix[q], v[q-1], ix[q-1])) {
                        float tv = v[q]; v[q] = v[q-1]; v[q-1] = tv;
                        int   ti = ix[q]; ix[q] = ix[q-1]; ix[q-1] = ti;
                    }
            }
        }
    }

    // write: idx block [TT*6] then weight block [TT*6], both as fp32.
    // weight = 16 * score  (x16 is a pure exponent shift: exact)
    if (sub == 0) {
        const long tokg = tok0 + token;
        #pragma unroll
        for (int j = 0; j < 6; ++j) {
            out[tokg * TOPK + j] = (float)ix[j];
            out[(long)TT * TOPK + tokg * TOPK + j] = 16.0f * v[j];
        }
    }
}

extern "C" void kernel_launch(void* const* d_in, const int* in_sizes, int n_in,
                              void* d_out, int out_size, void* d_ws, size_t ws_size,
                              hipStream_t stream) {
    const float* X = (const float*)d_in[0];   // hidden_states [4,4096,5120] fp32
    const float* W = (const float*)d_in[1];   // weight [160,5120] fp32
    float* out = (float*)d_out;               // [idx: 98304][weight: 98304] fp32
    gate_kernel<<<TT / BT, 256, 0, stream>>>(X, W, out);
}